// Round 2
// baseline (374.218 us; speedup 1.0000x reference)
//
#include <hip/hip_runtime.h>

// MovingAverageLayer: x (T=262144, F=64) fp32 -> out (T, 256) fp32
//   out[:,0:64]=x, out[:,64:128]=ma7, out[:,128:192]=ma30, out[:,192:256]=ma90
//   (expanding mean for i < period-1, windowed mean after)
//
// R1: float4 vectorization. Each lane owns 4 consecutive columns (16 B), so
// 16 lanes cover one row and each wave processes 4 chunks (one per 16-lane
// subgroup). Every vmem instruction moves 1 KiB/wave (16 B/lane) instead of
// 256 B -> 4x fewer memory instructions than the scalar R0 kernel.
// CHUNK=32 keeps 8192 chunks -> 2048 waves -> 8 waves/CU for latency hiding.
// All element indices fit int32 (max 16.8M float4), avoiding 64-bit muls.

#define T_ROWS 262144
#define CHUNK 32
#define XSTRIDE4 16    // x row stride in float4 (64 floats)
#define OSTRIDE4 64    // out row stride in float4 (256 floats)

__device__ __forceinline__ float4 f4add(float4 a, float4 b) {
    return make_float4(a.x + b.x, a.y + b.y, a.z + b.z, a.w + b.w);
}
__device__ __forceinline__ float4 f4sub(float4 a, float4 b) {
    return make_float4(a.x - b.x, a.y - b.y, a.z - b.z, a.w - b.w);
}
__device__ __forceinline__ float4 f4scale(float4 a, float s) {
    return make_float4(a.x * s, a.y * s, a.z * s, a.w * s);
}

__global__ __launch_bounds__(256) void ma_kernel(const float4* __restrict__ x,
                                                 float4* __restrict__ out) {
    const int tid  = threadIdx.x;
    const int lane = tid & 63;
    const int wave = tid >> 6;        // 0..3
    const int sub  = lane >> 4;       // 0..3: chunk subgroup within wave
    const int c    = lane & 15;       // float4 column within the row

    const int chunk = (blockIdx.x * 4 + wave) * 4 + sub;   // 16 chunks/block
    const int r0 = chunk * CHUNK;

    const float4* __restrict__ xc = x + c;    // + row*XSTRIDE4
    float4* __restrict__ oc = out + c;        // + row*OSTRIDE4

    float4 s7  = make_float4(0.f, 0.f, 0.f, 0.f);
    float4 s30 = s7, s90 = s7;

    if (r0 >= 90) {
        // ---- steady chunks: seed the 3 window sums from the 90 prior rows ----
        #pragma unroll
        for (int k = 1; k <= 7; ++k) {
            float4 v = xc[(r0 - k) * XSTRIDE4];
            s7 = f4add(s7, v); s30 = f4add(s30, v); s90 = f4add(s90, v);
        }
        #pragma unroll
        for (int k = 8; k <= 30; ++k) {
            float4 v = xc[(r0 - k) * XSTRIDE4];
            s30 = f4add(s30, v); s90 = f4add(s90, v);
        }
        #pragma unroll 6
        for (int k = 31; k <= 90; ++k) {
            s90 = f4add(s90, xc[(r0 - k) * XSTRIDE4]);
        }

        const float r7i = 1.f / 7.f, r30i = 1.f / 30.f, r90i = 1.f / 90.f;
        #pragma unroll 4
        for (int i = 0; i < CHUNK; ++i) {
            const int gi = r0 + i;
            float4 v   = xc[gi * XSTRIDE4];
            float4 o7  = xc[(gi - 7)  * XSTRIDE4];
            float4 o30 = xc[(gi - 30) * XSTRIDE4];
            float4 o90 = xc[(gi - 90) * XSTRIDE4];
            s7  = f4add(s7,  f4sub(v, o7));
            s30 = f4add(s30, f4sub(v, o30));
            s90 = f4add(s90, f4sub(v, o90));
            const int ob = gi * OSTRIDE4;
            oc[ob]      = v;
            oc[ob + 16] = f4scale(s7,  r7i);
            oc[ob + 32] = f4scale(s30, r30i);
            oc[ob + 48] = f4scale(s90, r90i);
        }
    } else {
        // ---- chunks 0..2 (r0 < 90): includes the expanding-mean region ----
        for (int i = 0; i < r0 + CHUNK; ++i) {
            float4 v = xc[i * XSTRIDE4];
            s7 = f4add(s7, v); s30 = f4add(s30, v); s90 = f4add(s90, v);
            if (i >= 7)  s7  = f4sub(s7,  xc[(i - 7)  * XSTRIDE4]);
            if (i >= 30) s30 = f4sub(s30, xc[(i - 30) * XSTRIDE4]);
            if (i >= 90) s90 = f4sub(s90, xc[(i - 90) * XSTRIDE4]);
            if (i >= r0) {
                float d7  = (i < 6)  ? 1.f / (float)(i + 1) : 1.f / 7.f;
                float d30 = (i < 29) ? 1.f / (float)(i + 1) : 1.f / 30.f;
                float d90 = (i < 89) ? 1.f / (float)(i + 1) : 1.f / 90.f;
                const int ob = i * OSTRIDE4;
                oc[ob]      = v;
                oc[ob + 16] = f4scale(s7,  d7);
                oc[ob + 32] = f4scale(s30, d30);
                oc[ob + 48] = f4scale(s90, d90);
            }
        }
    }
}

extern "C" void kernel_launch(void* const* d_in, const int* in_sizes, int n_in,
                              void* d_out, int out_size, void* d_ws, size_t ws_size,
                              hipStream_t stream) {
    const float4* x = (const float4*)d_in[0];
    float4* out = (float4*)d_out;
    const int n_chunks = T_ROWS / CHUNK;        // 8192
    const int n_blocks = n_chunks / 16;         // 512 blocks * 256 thr
    ma_kernel<<<n_blocks, 256, 0, stream>>>(x, out);
}